// Round 16
// baseline (472.001 us; speedup 1.0000x reference)
//
#include <hip/hip_runtime.h>
#include <math.h>

// ---------------- problem constants ----------------
#define V_VOX 12000
#define T_PTS 35
#define DD 10
#define HH 200
#define WW 176
#define EPSV 1e-5f

#define DP 12
#define HP 202
#define WP 178
#define PPLN (HP * WP)          // 35956 padded plane pixels
#define PVOX (DP * PPLN)        // 431472 padded volume pixels
#define NPIX (DD * HH * WW)     // 352000
#define HWPIX (HH * WW)         // 35200

typedef _Float16 half_t;
typedef _Float16 f16x8 __attribute__((ext_vector_type(8)));
typedef float f32x16 __attribute__((ext_vector_type(16)));

// ---------------- workspace layout (BYTE offsets, all 256-aligned) ----------------
#define WPA_OFF 0           // 27*1*2*2*512 halves = 110592 B
#define WPB_OFF 110592      // 27*2*2*2*512 halves = 221184 B
#define WPR1_OFF 331776     // 9*2*2*4*512 halves = 147456 B
#define STATS_OFF 479232    // 1024 floats
#define FEATS_OFF 483328    // 12000*32 f32 = 1536000 B
#define VOLP_OFF 2019328    // PVOX*32 halves = 27614208 B
#define X1P_OFF 29633536    // 2 planes * PVOX*32 halves = 55228416 B
#define Y_OFF 84861952      // NPIX*64 halves = 45056000 B  (y1 then y2)
#define PLANE_OFF 129917952 // 2 planes * PPLN*32 halves = 4602368 B
#define R1OUT_OFF 134520320 // HWPIX*128 halves = 9011200 B

// stats float sub-offsets
#define S_BN0S 0
#define S_BN0Q 32
#define S_BN1S 64
#define S_BN1Q 128
#define S_BN2S 192
#define S_BN2Q 256
#define C0A 320
#define C0B 352
#define C1A 384
#define C1B 448
#define C2A 512
#define C2B 576

// ---------------- global_load_lds helper (width 16, gfx950) ----------------
__device__ __forceinline__ void gload16(const half_t* g, half_t* l) {
    __builtin_amdgcn_global_load_lds(
        (const __attribute__((address_space(1))) void*)g,
        (__attribute__((address_space(3))) void*)l, 16, 0, 0);
}

// ---------------- weight pack for 32-wide octiles (mfma 32x32x16 B fragments) ----
// wp idx = ((((tap*KH + kh)*2 + khf)*OCT + ot)*64 + lane)*8 + j
// oc = ot*32 + (lane&31); ic = kh*32 + khf*16 + (lane>>5)*8 + j
__global__ void k_pack(const float* __restrict__ w, half_t* __restrict__ wp,
                       int IC, int NT, int OC) {
    int id = blockIdx.x * 256 + threadIdx.x;
    int OCT = OC >> 5, KH = IC >> 5;
    int total = NT * KH * 2 * OCT * 512;
    if (id >= total) return;
    int j = id & 7;
    int lane = (id >> 3) & 63;
    int rest = id >> 9;
    int ot = rest % OCT; rest /= OCT;
    int khf = rest & 1; rest >>= 1;
    int kh = rest % KH;
    int tap = rest / KH;
    int oc = ot * 32 + (lane & 31);
    int ic = kh * 32 + khf * 16 + (lane >> 5) * 8 + j;
    wp[id] = (half_t)w[(oc * IC + ic) * NT + tap];
}

// ---------------- VFE: BN0 batch stats ----------------
__global__ void k_vfe_stats(const float4* __restrict__ vox, const float* __restrict__ w_lin,
                            const float* __restrict__ b_lin, float* __restrict__ S) {
    int tid = blockIdx.x * 256 + threadIdx.x;
    int c = threadIdx.x & 31;
    float4 w = ((const float4*)w_lin)[c];
    float bl = b_lin[c];
    float s = 0.f, q = 0.f;
    const int np = V_VOX * T_PTS;
    int stride = gridDim.x * 8;
    for (int p = tid >> 5; p < np; p += stride) {
        float4 v = vox[p];
        float d = v.x * w.x + v.y * w.y + v.z * w.z + v.w * w.w + bl;
        s += d;
        q += d * d;
    }
    s += __shfl_xor(s, 32);
    q += __shfl_xor(q, 32);
    if ((threadIdx.x & 63) < 32) {
        atomicAdd(&S[S_BN0S + c], s);
        atomicAdd(&S[S_BN0Q + c], q);
    }
}

// ---------------- BN finalize ----------------
__global__ void k_bn_final(const float* __restrict__ ss, const float* __restrict__ sq,
                           const float* __restrict__ g, const float* __restrict__ be,
                           float* __restrict__ ca, float* __restrict__ cb, int C, float invN) {
    int c = threadIdx.x;
    if (c >= C) return;
    float m = ss[c] * invN;
    float v = sq[c] * invN - m * m;
    float a = g[c] * rsqrtf(v + EPSV);
    ca[c] = a;
    cb[c] = be[c] - m * a;
}

// ---------------- VFE: relu(bn(h)) max over T ----------------
__global__ void k_vfe_max(const float4* __restrict__ vox, const float* __restrict__ w_lin,
                          const float* __restrict__ b_lin, const float* __restrict__ ca,
                          const float* __restrict__ cb, float* __restrict__ feats) {
    int id = blockIdx.x * 256 + threadIdx.x;
    if (id >= V_VOX * 32) return;
    int c = id & 31;
    int v = id >> 5;
    float4 w = ((const float4*)w_lin)[c];
    float bl = b_lin[c], A = ca[c], B = cb[c];
    float m = 0.f;
    for (int t = 0; t < T_PTS; t++) {
        float4 p = vox[v * T_PTS + t];
        float d = p.x * w.x + p.y * w.y + p.z * w.z + p.w * w.w + bl;
        m = fmaxf(m, A * d + B);
    }
    feats[id] = m;
}

// ---------------- scatter feats into padded channel-last f16 volume ----------------
__global__ void k_scatter(const float* __restrict__ feats, const int* __restrict__ coords,
                          half_t* __restrict__ volp) {
    int id = blockIdx.x * 256 + threadIdx.x;
    if (id >= V_VOX * 32) return;
    int c = id & 31;
    int v = id >> 5;
    int z = coords[v * 3 + 0];
    int y = coords[v * 3 + 1];
    int x = coords[v * 3 + 2];
    volp[(((z + 1) * HP + (y + 1)) * WP + (x + 1)) * 32 + c] = (half_t)feats[id];
}

// ---------------- implicit-GEMM conv via MFMA f32_32x32x16_f16, 2x2 acc tile ----------------
// Block: 256 thr / 4 waves (wave = yg 0..3); tile 16x * 16y * 64oc.
// Wave owns 64 px (2 px-tiles of 16x*2y) x 64 oc (2 oc-tiles of 32): acc[2][2] f32x16.
// Per (khalf,dx,dy): read 2 Af + 2 Bf -> 4 independent MFMA (read:MFMA = 1:1, vs 2:1
// in all prior rounds -- the m97 fragment-reuse property).
// A lane map: row=(l&31)=yr*16+x, k=(l>>5)*8+j. B: col=l&31 (oc), k=(l>>5)*8+j.
// C/D: col=lane&31, row=(reg&3)+8*(reg>>2)+4*(lane>>5)  [HW-verified m74/m101].
// Per slab (dz,kh): stage A 18x18x32ch (20.7KB gload_lds, inverse-XOR-swizzled
// source; read swizzle byte^=(p&7)<<4) + B 36KB, vmcnt(0)+syncthreads, compute.
// LDS 57.6KB -> 2 blocks/CU; launch_bounds(256,2) -> VGPR cap 256 (~120 live).
template <int KH, int DZ, int OCT, bool RELU, bool STATS>
__global__ __launch_bounds__(256, 2) void k_conv(const half_t* __restrict__ in,
                                                 size_t khstride,
                                                 const half_t* __restrict__ wp,
                                                 const float* __restrict__ bias,
                                                 half_t* __restrict__ out,
                                                 float* __restrict__ ssum,
                                                 float* __restrict__ ssq) {
    constexpr int OCALL = OCT * 32;
    constexpr int NS = DZ * KH;
    __shared__ __align__(16) half_t tA[1296 * 8];   // 20736 B
    __shared__ __align__(16) half_t tB[36 * 512];   // 36864 B

    const int tid = threadIdx.x;
    const int lane = tid & 63;
    const int yg = tid >> 6;          // wave id = 4-row group
    const int x0 = blockIdx.x * 16;
    const int y0b = blockIdx.y * 16;
    const int bz = blockIdx.z;
    const int z0 = (DZ == 3) ? bz : 0;
    const int ocb = (DZ == 3) ? 0 : bz * 2;          // octile-of-32 base
    const bool valid = (y0b + yg * 4 < HH);
    const int xl = lane & 15;
    const int yrl = (lane >> 4) & 1;
    const int kg = (lane >> 5) & 1;

    // ---- A-stage inverse-swizzle decode (slab-invariant). Phys chunk c holds
    // logical (p,q) with phys_byte=(p*64+q*16)^((p&7)<<4):
    //   p0=((c>>2)^(c>>4))&1 ; p=((c>>3)<<1)|p0 ; q=(c&3)^(p&3)
    int gofsA[6]; bool okA[6];
#pragma unroll
    for (int r = 0; r < 6; ++r) {
        int c = tid + r * 256;
        okA[r] = (c < 1296);
        int cc = okA[r] ? c : 0;
        int p0 = ((cc >> 2) ^ (cc >> 4)) & 1;
        int p = ((cc >> 3) << 1) | p0;
        int q = (cc & 3) ^ (p & 3);
        int row = p / 18, px = p - row * 18;
        int grow = y0b + row;
        if (grow > HP - 1) grow = HP - 1;   // clamp; pad rows are zero
        gofsA[r] = (grow * WP + x0 + px) * 32 + q * 8;
    }

    f32x16 acc[2][2];
#pragma unroll
    for (int m = 0; m < 2; ++m)
#pragma unroll
        for (int n = 0; n < 2; ++n) acc[m][n] = (f32x16)(0.f);

    auto STAGE = [&](int s) {
        const int dz = s / KH, kh = s % KH;
        const half_t* sl = in + (size_t)kh * khstride
                           + (size_t)(z0 + dz) * (DZ == 3 ? (size_t)PPLN * 32 : 0);
#pragma unroll
        for (int r = 0; r < 6; ++r)
            if (okA[r]) gload16(sl + gofsA[r], &tA[(size_t)(tid + r * 256) * 8]);
#pragma unroll
        for (int r = 0; r < 9; ++r) {
            int c = tid + r * 256;                 // 0..2303
            int u = c >> 6;                        // wave-uniform unit id 0..35
            int l64 = c & 63;
            int tl = u >> 2, khf = (u >> 1) & 1, ot = u & 1;
            const half_t* g = wp + ((((size_t)(dz * 9 + tl) * KH + kh) * 2 + khf) * OCT
                                    + ocb + ot) * 512 + l64 * 8;
            gload16(g, &tB[(size_t)u * 512 + l64 * 8]);
        }
    };

#pragma unroll 1
    for (int s = 0; s < NS; ++s) {
        STAGE(s);
        asm volatile("s_waitcnt vmcnt(0)" ::: "memory");
        __syncthreads();

        if (valid) {
#pragma unroll
            for (int khalf = 0; khalf < 2; ++khalf) {
#pragma unroll
                for (int dx = 0; dx < 3; ++dx) {
#pragma unroll
                    for (int dy = 0; dy < 3; ++dy) {
                        int u = ((dy * 3 + dx) * 2 + khalf) * 2;
                        f16x8 Bf[2];
#pragma unroll
                        for (int n = 0; n < 2; ++n)
                            Bf[n] = *(const f16x8*)&tB[(u + n) * 512 + lane * 8];
                        f16x8 Af[2];
#pragma unroll
                        for (int m = 0; m < 2; ++m) {
                            int p = (yg * 4 + dy + 2 * m + yrl) * 18 + dx + xl;
                            int ph = ((p << 6) | ((khalf * 2 + kg) << 4)) ^ ((p & 7) << 4);
                            Af[m] = *(const f16x8*)((const char*)tA + ph);
                        }
#pragma unroll
                        for (int m = 0; m < 2; ++m)
#pragma unroll
                            for (int n = 0; n < 2; ++n)
                                acc[m][n] = __builtin_amdgcn_mfma_f32_32x32x16_f16(
                                    Af[m], Bf[n], acc[m][n], 0, 0, 0);
                    }
                }
            }
        }
        __syncthreads();
    }

    if (!valid) return;
    // epilogue: C/D col=lane&31 (oc); row rp=(reg&3)+8*(reg>>2)+4*kg -> x=rp&15, yr=rp>>4
    float sreg[2] = {0.f, 0.f}, qreg[2] = {0.f, 0.f};
#pragma unroll
    for (int n = 0; n < 2; ++n) {
        int oc = (ocb + n) * 32 + (lane & 31);
        float bv = bias[oc];
#pragma unroll
        for (int m = 0; m < 2; ++m) {
#pragma unroll
            for (int reg = 0; reg < 16; ++reg) {
                int rp = (reg & 3) + 8 * (reg >> 2) + 4 * kg;
                int xx = x0 + (rp & 15);
                int yy = y0b + yg * 4 + 2 * m + (rp >> 4);
                float v = acc[m][n][reg] + bv;
                if (STATS) { sreg[n] += v; qreg[n] += v * v; }
                float w = RELU ? fmaxf(v, 0.f) : v;
                out[((size_t)(z0 * HH + yy) * WW + xx) * OCALL + oc] = (half_t)w;
            }
        }
    }
    if (STATS) {
#pragma unroll
        for (int n = 0; n < 2; ++n) {
            float s = sreg[n], q = qreg[n];
            s += __shfl_xor(s, 32);
            q += __shfl_xor(q, 32);
            if (lane < 32) {
                int oc = (ocb + n) * 32 + lane;
                atomicAdd(&ssum[oc], s);
                atomicAdd(&ssq[oc], q);
            }
        }
    }
}

// ---------------- activate: x1p = relu(a*y1+b) into 2x 32-ch padded planes ----------------
__global__ void k_activate(const half_t* __restrict__ y1, const float* __restrict__ ca,
                           const float* __restrict__ cb, half_t* __restrict__ xp) {
    int id = blockIdx.x * 256 + threadIdx.x;
    if (id >= PVOX * 8) return;
    int c0 = (id & 7) * 8;
    int pix = id >> 3;
    int zp = pix / PPLN;
    int rem = pix - zp * PPLN;
    int yp = rem / WP;
    int xq = rem - yp * WP;
    f16x8 o;
    if (zp >= 1 && zp <= DD && yp >= 1 && yp <= HH && xq >= 1 && xq <= WW) {
        size_t p = ((size_t)((zp - 1) * HH + (yp - 1)) * WW + (xq - 1));
        f16x8 v = *(const f16x8*)(y1 + p * 64 + c0);
#pragma unroll
        for (int j = 0; j < 8; j++)
            o[j] = (half_t)fmaxf(ca[c0 + j] * (float)v[j] + cb[c0 + j], 0.f);
    } else {
#pragma unroll
        for (int j = 0; j < 8; j++) o[j] = (half_t)0.f;
    }
    int khp = c0 >> 5;
    *(f16x8*)(xp + (size_t)khp * PVOX * 32 + (size_t)pix * 32 + (c0 & 31)) = o;
}

// ---------------- BN2 + relu + depth mean -> 2x 32-ch padded planes ----------------
__global__ void k_depthmean(const half_t* __restrict__ y2, const float* __restrict__ ca,
                            const float* __restrict__ cb, half_t* __restrict__ plane) {
    int id = blockIdx.x * 256 + threadIdx.x;  // PPLN*64 = 2301184, divisible by 256
    int c = id & 63;
    int pix = id >> 6;
    int yp = pix / WP;
    int xq = pix - yp * WP;
    float val = 0.f;
    if (yp >= 1 && yp <= HH && xq >= 1 && xq <= WW) {
        float A = ca[c], B = cb[c], s = 0.f;
        const half_t* base = y2 + ((size_t)(yp - 1) * WW + (xq - 1)) * 64 + c;
#pragma unroll
        for (int z = 0; z < DD; z++)
            s += fmaxf(A * (float)base[(size_t)z * HWPIX * 64] + B, 0.f);
        val = s * 0.1f;
    }
    int khp = c >> 5;
    plane[(size_t)khp * PPLN * 32 + (size_t)pix * 32 + (c & 31)] = (half_t)val;
}

// ---------------- 1x1 conv 128->8 + box transforms ----------------
__global__ void k_r2(const half_t* __restrict__ r1o, const float* __restrict__ w,
                     const float* __restrict__ bias, float* __restrict__ outp) {
    __shared__ float wsm[1024];
    for (int i = threadIdx.x; i < 1024; i += 256) wsm[i] = w[i];
    __syncthreads();
    int p = blockIdx.x * 256 + threadIdx.x;
    if (p >= HWPIX) return;
    float acc[8];
#pragma unroll
    for (int o = 0; o < 8; o++) acc[o] = bias[o];
    const half_t* rb = r1o + (size_t)p * 128;
#pragma unroll 4
    for (int icb = 0; icb < 128; icb += 8) {
        f16x8 v = *(const f16x8*)(rb + icb);
#pragma unroll
        for (int j = 0; j < 8; j++) {
            float vv = (float)v[j];
#pragma unroll
            for (int o = 0; o < 8; o++) acc[o] += vv * wsm[o * 128 + icb + j];
        }
    }
    outp[0 * HWPIX + p] = acc[0];
    outp[1 * HWPIX + p] = acc[1];
    outp[2 * HWPIX + p] = acc[2];
    outp[3 * HWPIX + p] = expf(acc[3]);
    outp[4 * HWPIX + p] = expf(acc[4]);
    outp[5 * HWPIX + p] = expf(acc[5]);
    outp[6 * HWPIX + p] = tanhf(acc[6]);
    outp[7 * HWPIX + p] = 1.f / (1.f + expf(-acc[7]));
}

// ---------------- host launch ----------------
extern "C" void kernel_launch(void* const* d_in, const int* in_sizes, int n_in,
                              void* d_out, int out_size, void* d_ws, size_t ws_size,
                              hipStream_t stream) {
    const float4* voxels = (const float4*)d_in[0];
    const int* coords = (const int*)d_in[1];
    const float* w_lin = (const float*)d_in[2];
    const float* b_lin = (const float*)d_in[3];
    const float* g_bn0 = (const float*)d_in[4];
    const float* be_bn0 = (const float*)d_in[5];
    const float* w_c3a = (const float*)d_in[6];
    const float* b_c3a = (const float*)d_in[7];
    const float* g_bn1 = (const float*)d_in[8];
    const float* be_bn1 = (const float*)d_in[9];
    const float* w_c3b = (const float*)d_in[10];
    const float* b_c3b = (const float*)d_in[11];
    const float* g_bn2 = (const float*)d_in[12];
    const float* be_bn2 = (const float*)d_in[13];
    const float* w_r1 = (const float*)d_in[14];
    const float* b_r1 = (const float*)d_in[15];
    const float* w_r2 = (const float*)d_in[16];
    const float* b_r2 = (const float*)d_in[17];

    char* ws = (char*)d_ws;
    half_t* wpA = (half_t*)(ws + WPA_OFF);
    half_t* wpB = (half_t*)(ws + WPB_OFF);
    half_t* wpR1 = (half_t*)(ws + WPR1_OFF);
    float* S = (float*)(ws + STATS_OFF);
    float* feats = (float*)(ws + FEATS_OFF);
    half_t* volp = (half_t*)(ws + VOLP_OFF);
    half_t* x1p = (half_t*)(ws + X1P_OFF);
    half_t* Y = (half_t*)(ws + Y_OFF);
    half_t* plane = (half_t*)(ws + PLANE_OFF);
    half_t* r1out = (half_t*)(ws + R1OUT_OFF);
    float* outp = (float*)d_out;

    hipMemsetAsync(S, 0, 320 * sizeof(float), stream);
    hipMemsetAsync(volp, 0, (size_t)PVOX * 32 * sizeof(half_t), stream);

    // weight packs (32-wide octile fragment order)
    k_pack<<<216, 256, 0, stream>>>(w_c3a, wpA, 32, 27, 64);
    k_pack<<<432, 256, 0, stream>>>(w_c3b, wpB, 64, 27, 64);
    k_pack<<<288, 256, 0, stream>>>(w_r1, wpR1, 64, 9, 128);

    // VFE
    k_vfe_stats<<<512, 256, 0, stream>>>(voxels, w_lin, b_lin, S);
    k_bn_final<<<1, 64, 0, stream>>>(S + S_BN0S, S + S_BN0Q, g_bn0, be_bn0,
                                     S + C0A, S + C0B, 32, 1.f / 420000.f);
    k_vfe_max<<<1500, 256, 0, stream>>>(voxels, w_lin, b_lin, S + C0A, S + C0B, feats);
    k_scatter<<<1500, 256, 0, stream>>>(feats, coords, volp);

    // conv3a (IC=32) -> y1 f16 [p][64], fused BN1 stats
    k_conv<1, 3, 2, false, true><<<dim3(11, 13, 10), 256, 0, stream>>>(
        volp, 0, wpA, b_c3a, Y, S + S_BN1S, S + S_BN1Q);
    k_bn_final<<<1, 64, 0, stream>>>(S + S_BN1S, S + S_BN1Q, g_bn1, be_bn1,
                                     S + C1A, S + C1B, 64, 1.f / 352000.f);
    k_activate<<<13484, 256, 0, stream>>>(Y, S + C1A, S + C1B, x1p);

    // conv3b (IC=64 as 2x32-ch planes) -> y2 f16 [p][64], fused BN2 stats
    k_conv<2, 3, 2, false, true><<<dim3(11, 13, 10), 256, 0, stream>>>(
        x1p, (size_t)PVOX * 32, wpB, b_c3b, Y, S + S_BN2S, S + S_BN2Q);
    k_bn_final<<<1, 64, 0, stream>>>(S + S_BN2S, S + S_BN2Q, g_bn2, be_bn2,
                                     S + C2A, S + C2B, 64, 1.f / 352000.f);

    // BN2+relu+depth-mean -> 2x 32-ch padded planes
    k_depthmean<<<8989, 256, 0, stream>>>(Y, S + C2A, S + C2B, plane);

    // RPN: r1 (2D conv, 128 oc -> 2 z-groups of 64 oc) + relu -> [p][128] f16
    k_conv<2, 1, 4, true, false><<<dim3(11, 13, 2), 256, 0, stream>>>(
        plane, (size_t)PPLN * 32, wpR1, b_r1, r1out, nullptr, nullptr);
    k_r2<<<138, 256, 0, stream>>>(r1out, w_r2, b_r2, outp);
}

// Round 17
// 450.057 us; speedup vs baseline: 1.0488x; 1.0488x over previous
//
#include <hip/hip_runtime.h>
#include <math.h>

// ---------------- problem constants ----------------
#define V_VOX 12000
#define T_PTS 35
#define DD 10
#define HH 200
#define WW 176
#define EPSV 1e-5f

#define DP 12
#define HP 202
#define WP 178
#define PPLN (HP * WP)          // 35956 padded plane pixels
#define PVOX (DP * PPLN)        // 431472 padded volume pixels
#define NPIX (DD * HH * WW)     // 352000
#define HWPIX (HH * WW)         // 35200

typedef _Float16 half_t;
typedef _Float16 f16x8 __attribute__((ext_vector_type(8)));
typedef float f32x4 __attribute__((ext_vector_type(4)));

// ---------------- workspace layout (BYTE offsets, all 256-aligned) ----------------
#define WPA_OFF 0           // 27*1*4*512 halves = 110592 B
#define WPB_OFF 110592      // 27*2*4*512 halves = 221184 B
#define WPR1_OFF 331776     // 9*2*8*512 halves = 147456 B
#define STATS_OFF 479232    // 1024 floats
#define VOLP_OFF 2019328    // PVOX*32 halves = 27614208 B
#define X1P_OFF 29633536    // 2 planes * PVOX*32 halves = 55228416 B
#define Y_OFF 84861952      // NPIX*64 halves = 45056000 B  (y1 then y2)
#define PLANE_OFF 129917952 // 2 planes * PPLN*32 halves = 4602368 B
#define R1OUT_OFF 134520320 // HWPIX*128 halves = 9011200 B

// stats float sub-offsets
#define S_BN0S 0
#define S_BN0Q 32
#define S_BN1S 64
#define S_BN1Q 128
#define S_BN2S 192
#define S_BN2Q 256

// ---------------- global_load_lds helper (width 16, gfx950) ----------------
__device__ __forceinline__ void gload16(const half_t* g, half_t* l) {
    __builtin_amdgcn_global_load_lds(
        (const __attribute__((address_space(1))) void*)g,
        (__attribute__((address_space(3))) void*)l, 16, 0, 0);
}

// ---------------- weight pack: w[oc][ic][tap] -> per-lane MFMA B fragments ----------------
// wp index = (((tap*KH + kh)*OCT + ot)*64 + lane)*8 + j
// oc = ot*16 + (lane&15); ic = kh*32 + (lane>>4)*8 + j
__global__ void k_pack(const float* __restrict__ w, half_t* __restrict__ wp,
                       int IC, int NT, int OC) {
    int id = blockIdx.x * 256 + threadIdx.x;
    int OCT = OC >> 4, KH = IC >> 5;
    int total = NT * KH * OCT * 512;
    if (id >= total) return;
    int j = id & 7;
    int lane = (id >> 3) & 63;
    int rest = id >> 9;
    int ot = rest % OCT; rest /= OCT;
    int kh = rest % KH;
    int tap = rest / KH;
    int oc = ot * 16 + (lane & 15);
    int ic = kh * 32 + (lane >> 4) * 8 + j;
    wp[id] = (half_t)w[(oc * IC + ic) * NT + tap];
}

// ---------------- VFE: BN0 batch stats ----------------
__global__ void k_vfe_stats(const float4* __restrict__ vox, const float* __restrict__ w_lin,
                            const float* __restrict__ b_lin, float* __restrict__ S) {
    int tid = blockIdx.x * 256 + threadIdx.x;
    int c = threadIdx.x & 31;
    float4 w = ((const float4*)w_lin)[c];
    float bl = b_lin[c];
    float s = 0.f, q = 0.f;
    const int np = V_VOX * T_PTS;
    int stride = gridDim.x * 8;
    for (int p = tid >> 5; p < np; p += stride) {
        float4 v = vox[p];
        float d = v.x * w.x + v.y * w.y + v.z * w.z + v.w * w.w + bl;
        s += d;
        q += d * d;
    }
    s += __shfl_xor(s, 32);
    q += __shfl_xor(q, 32);
    if ((threadIdx.x & 63) < 32) {
        atomicAdd(&S[S_BN0S + c], s);
        atomicAdd(&S[S_BN0Q + c], q);
    }
}

// ---------------- VFE: relu(bn(h)) max over T, scattered directly into volume ----------------
// BN0 coeffs computed per-block from raw sums (k_bn_final folded in).
__global__ void k_vfe_max(const float4* __restrict__ vox, const float* __restrict__ w_lin,
                          const float* __restrict__ b_lin, const float* __restrict__ S,
                          const float* __restrict__ g, const float* __restrict__ be,
                          const int* __restrict__ coords, half_t* __restrict__ volp) {
    __shared__ float lA[32], lB[32];
    if (threadIdx.x < 32) {
        int c = threadIdx.x;
        float m = S[S_BN0S + c] * (1.f / 420000.f);
        float v = S[S_BN0Q + c] * (1.f / 420000.f) - m * m;
        float a = g[c] * rsqrtf(v + EPSV);
        lA[c] = a;
        lB[c] = be[c] - m * a;
    }
    __syncthreads();
    int id = blockIdx.x * 256 + threadIdx.x;
    if (id >= V_VOX * 32) return;
    int c = id & 31;
    int v = id >> 5;
    float4 w = ((const float4*)w_lin)[c];
    float bl = b_lin[c], A = lA[c], B = lB[c];
    float m = 0.f;
    for (int t = 0; t < T_PTS; t++) {
        float4 p = vox[v * T_PTS + t];
        float d = p.x * w.x + p.y * w.y + p.z * w.z + p.w * w.w + bl;
        m = fmaxf(m, A * d + B);
    }
    int z = coords[v * 3 + 0];
    int y = coords[v * 3 + 1];
    int x = coords[v * 3 + 2];
    volp[(((z + 1) * HP + (y + 1)) * WP + (x + 1)) * 32 + c] = (half_t)m;
}

// ---------------- implicit-GEMM conv: gload_lds staging + XOR-swizzled A (r9 best) ----------------
// Block: 256 thr / 4 waves; output tile 16x * 16y * 32oc (2 octiles; oc-split in grid.z).
// Per slab (dz,kh): stage A (18x18 px x 32ch = 20.7KB, LINEAR dest via global_load_lds,
// read-side XOR swizzle byte[6:4]^=pix[2:0], stage-side inverse-permuted per-lane
// GLOBAL offsets precomputed) + B (9 taps x 2 octiles = 18KB, linear both sides).
// LDS 39.9KB -> 4 blocks/CU = 16 waves/CU; staging uses zero VGPRs (DMA).
template <int KH, int DZ, int OCTP, bool RELU, bool STATS>
__global__ __launch_bounds__(256, 4) void k_conv(const half_t* __restrict__ in,
                                                 size_t khstride,
                                                 const half_t* __restrict__ wp,
                                                 const float* __restrict__ bias,
                                                 half_t* __restrict__ out,
                                                 float* __restrict__ ssum,
                                                 float* __restrict__ ssq) {
    constexpr int OC = OCTP * 16;
    constexpr int NS = DZ * KH;
    __shared__ __align__(16) half_t tA[21 * 512];  // 21504 B
    __shared__ __align__(16) half_t tB[18 * 512];  // 18432 B

    const int tid = threadIdx.x;
    const int lane = tid & 63;
    const int wv = tid >> 6;
    const int x0 = blockIdx.x * 16;
    const int y0b = blockIdx.y * 16;
    const int bz = blockIdx.z;
    const int z0 = (DZ == 3) ? (bz >> 1) : 0;
    const int ocb = (DZ == 3) ? (bz & 1) * 2 : bz * 2;   // octile base (2 per block)
    const int y0w = y0b + wv * 4;
    const bool valid = (y0w < HH);
    const int colc = lane & 15, grp = lane >> 4;

    // ---- precompute A-stage per-lane global offsets (slab-invariant, halves) ----
    // LDS phys chunk c=run*64+lane holds logical (pix,q) with
    // phys_byte = (pix<<6 | q<<4) ^ ((pix&7)<<4); inverted here.
    unsigned gofsA[6];
#pragma unroll
    for (int i = 0; i < 6; ++i) {
        int run = wv + 4 * i;
        int c = run * 64 + lane;
        if (c > 1295) c = 1295;
        int pixhi = c >> 3, s = c & 7;
        int b = ((s >> 2) ^ (pixhi >> 1)) & 1;
        int q = ((s ^ b) & 1) | ((((s >> 1) ^ pixhi) & 1) << 1);
        int pix = pixhi * 2 + b;
        int row = pix / 18, px = pix - row * 18;
        int srow = y0b + row;
        if (srow > HP - 1) srow = HP - 1;  // clamp; pad rows are zero
        gofsA[i] = (unsigned)((srow * WP + x0 + px) * 32 + q * 8);
    }

    f32x4 acc[4][2];
#pragma unroll
    for (int m = 0; m < 4; m++)
#pragma unroll
        for (int n = 0; n < 2; n++) acc[m][n] = (f32x4)(0.f);

#pragma unroll 1
    for (int s = 0; s < NS; ++s) {
        const int dz = s / KH, kh = s % KH;
        const half_t* sl = in + (size_t)kh * khstride
                           + (size_t)(z0 + dz) * (DZ == 3 ? (size_t)PPLN * 32 : 0);
        // ---- stage A via global_load_lds (linear dest, pre-swizzled source) ----
#pragma unroll
        for (int i = 0; i < 6; ++i) {
            int run = wv + 4 * i;
            if (run < 21) gload16(sl + gofsA[i], &tA[run * 512]);
        }
        // ---- stage B: 9 taps x 2 octiles, contiguous runs ----
#pragma unroll
        for (int i = 0; i < 5; ++i) {
            int r = wv + 4 * i;
            if (r < 18) {
                int tap = r >> 1, hf = r & 1;
                const half_t* g = wp + (((size_t)(dz * 9 + tap) * KH + kh) * OCTP + ocb + hf) * 512
                                  + lane * 8;
                gload16(g, &tB[r * 512]);
            }
        }
        asm volatile("s_waitcnt vmcnt(0)" ::: "memory");
        __syncthreads();

        if (valid) {
#pragma unroll
            for (int dx = 0; dx < 3; ++dx) {
                f16x8 Af[6];
#pragma unroll
                for (int r = 0; r < 6; ++r) {
                    int pix = (wv * 4 + r) * 18 + colc + dx;
                    int ah = ((pix << 5) | (grp << 3)) ^ ((pix & 7) << 3);
                    Af[r] = *(const f16x8*)&tA[ah];
                }
#pragma unroll
                for (int dy = 0; dy < 3; ++dy) {
                    f16x8 Bf[2];
#pragma unroll
                    for (int n = 0; n < 2; ++n)
                        Bf[n] = *(const f16x8*)&tB[((dy * 3 + dx) * 2 + n) * 512 + lane * 8];
#pragma unroll
                    for (int m = 0; m < 4; ++m)
#pragma unroll
                        for (int n = 0; n < 2; ++n)
                            acc[m][n] = __builtin_amdgcn_mfma_f32_16x16x32_f16(
                                Af[dy + m], Bf[n], acc[m][n], 0, 0, 0);
                }
            }
        }
        __syncthreads();
    }

    if (!valid) return;
    // epilogue: C/D layout col=lane&15 (oc), row=(lane>>4)*4+i (x)
#pragma unroll
    for (int n = 0; n < 2; ++n) {
        int oc = (ocb + n) * 16 + colc;
        float bv = bias[oc];
        float s = 0.f, q = 0.f;
#pragma unroll
        for (int m = 0; m < 4; ++m) {
            int yy = y0w + m;
#pragma unroll
            for (int i = 0; i < 4; ++i) {
                int xx = x0 + grp * 4 + i;
                float v = acc[m][n][i] + bv;
                if (STATS) { s += v; q += v * v; }
                float w = RELU ? fmaxf(v, 0.f) : v;
                out[((size_t)(z0 * HH + yy) * WW + xx) * OC + oc] = (half_t)w;
            }
        }
        if (STATS) {
            s += __shfl_xor(s, 16); s += __shfl_xor(s, 32);
            q += __shfl_xor(q, 16); q += __shfl_xor(q, 32);
            if (lane < 16) {
                atomicAdd(&ssum[oc], s);
                atomicAdd(&ssq[oc], q);
            }
        }
    }
}

// ---------------- activate: x1p = relu(bn1(y1)) into 2x 32-ch padded planes ----------------
// BN1 coeffs computed per-block from raw sums (k_bn_final folded in).
__global__ void k_activate(const half_t* __restrict__ y1, const float* __restrict__ S,
                           const float* __restrict__ g, const float* __restrict__ be,
                           half_t* __restrict__ xp) {
    __shared__ float lA[64], lB[64];
    if (threadIdx.x < 64) {
        int c = threadIdx.x;
        float m = S[S_BN1S + c] * (1.f / 352000.f);
        float v = S[S_BN1Q + c] * (1.f / 352000.f) - m * m;
        float a = g[c] * rsqrtf(v + EPSV);
        lA[c] = a;
        lB[c] = be[c] - m * a;
    }
    __syncthreads();
    int id = blockIdx.x * 256 + threadIdx.x;
    if (id >= PVOX * 8) return;
    int c0 = (id & 7) * 8;
    int pix = id >> 3;
    int zp = pix / PPLN;
    int rem = pix - zp * PPLN;
    int yp = rem / WP;
    int xq = rem - yp * WP;
    f16x8 o;
    if (zp >= 1 && zp <= DD && yp >= 1 && yp <= HH && xq >= 1 && xq <= WW) {
        size_t p = ((size_t)((zp - 1) * HH + (yp - 1)) * WW + (xq - 1));
        f16x8 v = *(const f16x8*)(y1 + p * 64 + c0);
#pragma unroll
        for (int j = 0; j < 8; j++)
            o[j] = (half_t)fmaxf(lA[c0 + j] * (float)v[j] + lB[c0 + j], 0.f);
    } else {
#pragma unroll
        for (int j = 0; j < 8; j++) o[j] = (half_t)0.f;
    }
    int khp = c0 >> 5;
    *(f16x8*)(xp + (size_t)khp * PVOX * 32 + (size_t)pix * 32 + (c0 & 31)) = o;
}

// ---------------- BN2 + relu + depth mean (vectorized f16x8) -> 2x 32-ch padded planes ----------------
__global__ void k_depthmean(const half_t* __restrict__ y2, const float* __restrict__ S,
                            const float* __restrict__ g, const float* __restrict__ be,
                            half_t* __restrict__ plane) {
    __shared__ float lA[64], lB[64];
    if (threadIdx.x < 64) {
        int c = threadIdx.x;
        float m = S[S_BN2S + c] * (1.f / 352000.f);
        float v = S[S_BN2Q + c] * (1.f / 352000.f) - m * m;
        float a = g[c] * rsqrtf(v + EPSV);
        lA[c] = a;
        lB[c] = be[c] - m * a;
    }
    __syncthreads();
    int id = blockIdx.x * 256 + threadIdx.x;   // PPLN*8 = 287648 threads
    if (id >= PPLN * 8) return;
    int c8 = id & 7;
    int pix = id >> 3;
    int yp = pix / WP;
    int xq = pix - yp * WP;
    f16x8 o;
    if (yp >= 1 && yp <= HH && xq >= 1 && xq <= WW) {
        float A[8], B[8], sacc[8];
#pragma unroll
        for (int j = 0; j < 8; j++) {
            A[j] = lA[c8 * 8 + j];
            B[j] = lB[c8 * 8 + j];
            sacc[j] = 0.f;
        }
        const half_t* base = y2 + ((size_t)(yp - 1) * WW + (xq - 1)) * 64 + c8 * 8;
#pragma unroll
        for (int z = 0; z < DD; z++) {
            f16x8 v = *(const f16x8*)(base + (size_t)z * HWPIX * 64);
#pragma unroll
            for (int j = 0; j < 8; j++)
                sacc[j] += fmaxf(A[j] * (float)v[j] + B[j], 0.f);
        }
#pragma unroll
        for (int j = 0; j < 8; j++) o[j] = (half_t)(sacc[j] * 0.1f);
    } else {
#pragma unroll
        for (int j = 0; j < 8; j++) o[j] = (half_t)0.f;
    }
    int khp = c8 >> 2;
    *(f16x8*)(plane + (size_t)khp * PPLN * 32 + (size_t)pix * 32 + (c8 & 3) * 8) = o;
}

// ---------------- 1x1 conv 128->8 + box transforms ----------------
__global__ void k_r2(const half_t* __restrict__ r1o, const float* __restrict__ w,
                     const float* __restrict__ bias, float* __restrict__ outp) {
    __shared__ float wsm[1024];
    for (int i = threadIdx.x; i < 1024; i += 256) wsm[i] = w[i];
    __syncthreads();
    int p = blockIdx.x * 256 + threadIdx.x;
    if (p >= HWPIX) return;
    float acc[8];
#pragma unroll
    for (int o = 0; o < 8; o++) acc[o] = bias[o];
    const half_t* rb = r1o + (size_t)p * 128;
#pragma unroll 4
    for (int icb = 0; icb < 128; icb += 8) {
        f16x8 v = *(const f16x8*)(rb + icb);
#pragma unroll
        for (int j = 0; j < 8; j++) {
            float vv = (float)v[j];
#pragma unroll
            for (int o = 0; o < 8; o++) acc[o] += vv * wsm[o * 128 + icb + j];
        }
    }
    outp[0 * HWPIX + p] = acc[0];
    outp[1 * HWPIX + p] = acc[1];
    outp[2 * HWPIX + p] = acc[2];
    outp[3 * HWPIX + p] = expf(acc[3]);
    outp[4 * HWPIX + p] = expf(acc[4]);
    outp[5 * HWPIX + p] = expf(acc[5]);
    outp[6 * HWPIX + p] = tanhf(acc[6]);
    outp[7 * HWPIX + p] = 1.f / (1.f + expf(-acc[7]));
}

// ---------------- host launch ----------------
extern "C" void kernel_launch(void* const* d_in, const int* in_sizes, int n_in,
                              void* d_out, int out_size, void* d_ws, size_t ws_size,
                              hipStream_t stream) {
    const float4* voxels = (const float4*)d_in[0];
    const int* coords = (const int*)d_in[1];
    const float* w_lin = (const float*)d_in[2];
    const float* b_lin = (const float*)d_in[3];
    const float* g_bn0 = (const float*)d_in[4];
    const float* be_bn0 = (const float*)d_in[5];
    const float* w_c3a = (const float*)d_in[6];
    const float* b_c3a = (const float*)d_in[7];
    const float* g_bn1 = (const float*)d_in[8];
    const float* be_bn1 = (const float*)d_in[9];
    const float* w_c3b = (const float*)d_in[10];
    const float* b_c3b = (const float*)d_in[11];
    const float* g_bn2 = (const float*)d_in[12];
    const float* be_bn2 = (const float*)d_in[13];
    const float* w_r1 = (const float*)d_in[14];
    const float* b_r1 = (const float*)d_in[15];
    const float* w_r2 = (const float*)d_in[16];
    const float* b_r2 = (const float*)d_in[17];

    char* ws = (char*)d_ws;
    half_t* wpA = (half_t*)(ws + WPA_OFF);
    half_t* wpB = (half_t*)(ws + WPB_OFF);
    half_t* wpR1 = (half_t*)(ws + WPR1_OFF);
    float* S = (float*)(ws + STATS_OFF);
    half_t* volp = (half_t*)(ws + VOLP_OFF);
    half_t* x1p = (half_t*)(ws + X1P_OFF);
    half_t* Y = (half_t*)(ws + Y_OFF);
    half_t* plane = (half_t*)(ws + PLANE_OFF);
    half_t* r1out = (half_t*)(ws + R1OUT_OFF);
    float* outp = (float*)d_out;

    hipMemsetAsync(S, 0, 320 * sizeof(float), stream);
    hipMemsetAsync(volp, 0, (size_t)PVOX * 32 * sizeof(half_t), stream);

    // weight packs
    k_pack<<<216, 256, 0, stream>>>(w_c3a, wpA, 32, 27, 64);
    k_pack<<<432, 256, 0, stream>>>(w_c3b, wpB, 64, 27, 64);
    k_pack<<<288, 256, 0, stream>>>(w_r1, wpR1, 64, 9, 128);

    // VFE (BN0 coeffs folded into k_vfe_max; scatter fused)
    k_vfe_stats<<<512, 256, 0, stream>>>(voxels, w_lin, b_lin, S);
    k_vfe_max<<<1500, 256, 0, stream>>>(voxels, w_lin, b_lin, S, g_bn0, be_bn0,
                                        coords, volp);

    // conv3a (IC=32) -> y1 f16 [p][64], fused BN1 stats; z = 10 dz x 2 oc-halves
    k_conv<1, 3, 4, false, true><<<dim3(11, 13, 20), 256, 0, stream>>>(
        volp, 0, wpA, b_c3a, Y, S + S_BN1S, S + S_BN1Q);
    k_activate<<<13484, 256, 0, stream>>>(Y, S, g_bn1, be_bn1, x1p);

    // conv3b (IC=64 as 2x32-ch planes) -> y2 f16 [p][64], fused BN2 stats
    k_conv<2, 3, 4, false, true><<<dim3(11, 13, 20), 256, 0, stream>>>(
        x1p, (size_t)PVOX * 32, wpB, b_c3b, Y, S + S_BN2S, S + S_BN2Q);

    // BN2+relu+depth-mean (vectorized) -> 2x 32-ch padded planes
    k_depthmean<<<1124, 256, 0, stream>>>(Y, S, g_bn2, be_bn2, plane);

    // RPN: r1 (2D conv, 128 oc -> 4 z-groups of 2 octiles) + relu -> [p][128] f16
    k_conv<2, 1, 8, true, false><<<dim3(11, 13, 4), 256, 0, stream>>>(
        plane, (size_t)PPLN * 32, wpR1, b_r1, r1out, nullptr, nullptr);
    k_r2<<<138, 256, 0, stream>>>(r1out, w_r2, b_r2, outp);
}

// Round 18
// 446.021 us; speedup vs baseline: 1.0582x; 1.0090x over previous
//
#include <hip/hip_runtime.h>
#include <math.h>

// ---------------- problem constants ----------------
#define V_VOX 12000
#define T_PTS 35
#define DD 10
#define HH 200
#define WW 176
#define EPSV 1e-5f

#define DP 12
#define HP 202
#define WP 178
#define PPLN (HP * WP)          // 35956 padded plane pixels
#define PVOX (DP * PPLN)        // 431472 padded volume pixels
#define NPIX (DD * HH * WW)     // 352000
#define HWPIX (HH * WW)         // 35200

typedef _Float16 half_t;
typedef _Float16 f16x8 __attribute__((ext_vector_type(8)));
typedef float f32x4 __attribute__((ext_vector_type(4)));

// ---------------- workspace layout (BYTE offsets, all 256-aligned) ----------------
#define WPA_OFF 0           // 27*1*4*512 halves = 110592 B
#define WPB_OFF 110592      // 27*2*4*512 halves = 221184 B
#define WPR1_OFF 331776     // 9*2*8*512 halves = 147456 B
#define STATS_OFF 479232    // 1024 floats
#define VOLP_OFF 2019328    // PVOX*32 halves = 27614208 B
#define X1P_OFF 29633536    // 2 planes * PVOX*32 halves = 55228416 B
#define Y_OFF 84861952      // NPIX*64 halves = 45056000 B  (y1 then y2)
#define PLANE_OFF 129917952 // 2 planes * PPLN*32 halves = 4602368 B
#define R1OUT_OFF 134520320 // HWPIX*128 halves = 9011200 B

// stats float sub-offsets
#define S_BN0S 0
#define S_BN0Q 32
#define S_BN1S 64
#define S_BN1Q 128
#define S_BN2S 192
#define S_BN2Q 256

// ---------------- global_load_lds helper (width 16, gfx950) ----------------
__device__ __forceinline__ void gload16(const half_t* g, half_t* l) {
    __builtin_amdgcn_global_load_lds(
        (const __attribute__((address_space(1))) void*)g,
        (__attribute__((address_space(3))) void*)l, 16, 0, 0);
}

// ---------------- weight pack (all three nets in one launch) ----------------
// wp index = (((tap*KH + kh)*OCT + ot)*64 + lane)*8 + j
// oc = ot*16 + (lane&15); ic = kh*32 + (lane>>4)*8 + j
__device__ __forceinline__ void pack1(const float* __restrict__ w, half_t* __restrict__ wp,
                                      int IC, int NT, int OC, int id) {
    int OCT = OC >> 4, KH = IC >> 5;
    int j = id & 7;
    int lane = (id >> 3) & 63;
    int rest = id >> 9;
    int ot = rest % OCT; rest /= OCT;
    int kh = rest % KH;
    int tap = rest / KH;
    int oc = ot * 16 + (lane & 15);
    int ic = kh * 32 + (lane >> 4) * 8 + j;
    wp[id] = (half_t)w[(oc * IC + ic) * NT + tap];
}

__global__ void k_pack_all(const float* __restrict__ wA, const float* __restrict__ wB,
                           const float* __restrict__ wR1, half_t* __restrict__ wpA,
                           half_t* __restrict__ wpB, half_t* __restrict__ wpR1) {
    int id = blockIdx.x * 256 + threadIdx.x;
    if (id < 55296) pack1(wA, wpA, 32, 27, 64, id);
    else if (id < 165888) pack1(wB, wpB, 64, 27, 64, id - 55296);
    else if (id < 239616) pack1(wR1, wpR1, 64, 9, 128, id - 165888);
}

// ---------------- VFE: BN0 batch stats ----------------
__global__ void k_vfe_stats(const float4* __restrict__ vox, const float* __restrict__ w_lin,
                            const float* __restrict__ b_lin, float* __restrict__ S) {
    int tid = blockIdx.x * 256 + threadIdx.x;
    int c = threadIdx.x & 31;
    float4 w = ((const float4*)w_lin)[c];
    float bl = b_lin[c];
    float s = 0.f, q = 0.f;
    const int np = V_VOX * T_PTS;
    int stride = gridDim.x * 8;
    for (int p = tid >> 5; p < np; p += stride) {
        float4 v = vox[p];
        float d = v.x * w.x + v.y * w.y + v.z * w.z + v.w * w.w + bl;
        s += d;
        q += d * d;
    }
    s += __shfl_xor(s, 32);
    q += __shfl_xor(q, 32);
    if ((threadIdx.x & 63) < 32) {
        atomicAdd(&S[S_BN0S + c], s);
        atomicAdd(&S[S_BN0Q + c], q);
    }
}

// ---------------- VFE: relu(bn(h)) max over T, scattered directly into volume ----------------
__global__ void k_vfe_max(const float4* __restrict__ vox, const float* __restrict__ w_lin,
                          const float* __restrict__ b_lin, const float* __restrict__ S,
                          const float* __restrict__ g, const float* __restrict__ be,
                          const int* __restrict__ coords, half_t* __restrict__ volp) {
    __shared__ float lA[32], lB[32];
    if (threadIdx.x < 32) {
        int c = threadIdx.x;
        float m = S[S_BN0S + c] * (1.f / 420000.f);
        float v = S[S_BN0Q + c] * (1.f / 420000.f) - m * m;
        float a = g[c] * rsqrtf(v + EPSV);
        lA[c] = a;
        lB[c] = be[c] - m * a;
    }
    __syncthreads();
    int id = blockIdx.x * 256 + threadIdx.x;
    if (id >= V_VOX * 32) return;
    int c = id & 31;
    int v = id >> 5;
    float4 w = ((const float4*)w_lin)[c];
    float bl = b_lin[c], A = lA[c], B = lB[c];
    float m = 0.f;
    for (int t = 0; t < T_PTS; t++) {
        float4 p = vox[v * T_PTS + t];
        float d = p.x * w.x + p.y * w.y + p.z * w.z + p.w * w.w + bl;
        m = fmaxf(m, A * d + B);
    }
    int z = coords[v * 3 + 0];
    int y = coords[v * 3 + 1];
    int x = coords[v * 3 + 2];
    volp[(((z + 1) * HP + (y + 1)) * WP + (x + 1)) * 32 + c] = (half_t)m;
}

// ---------------- implicit-GEMM conv: r9 structure + T1 XCD-bijective block swizzle ----------------
// 1-D grid of NWG blocks. Work decode (oc-half INNERMOST so the A-sharing pair is
// consecutive in work id); bijective XCD remap (m204): each XCD owns a contiguous
// work chunk -> the oc pair + z-neighbors hit the same XCD's L2 (halves A HBM refetch).
// Per slab (dz,kh): stage A (20.7KB, gload_lds linear dest, read-side XOR swizzle
// byte[6:4]^=pix[2:0], inverse-permuted global sources) + B (18KB contiguous),
// vmcnt(0)+syncthreads, 72 MFMA/wave. LDS 39.9KB -> 4 blocks/CU.
template <int KH, int DZ, int OCTP, int NWG, bool RELU, bool STATS>
__global__ __launch_bounds__(256, 4) void k_conv(const half_t* __restrict__ in,
                                                 size_t khstride,
                                                 const half_t* __restrict__ wp,
                                                 const float* __restrict__ bias,
                                                 half_t* __restrict__ out,
                                                 float* __restrict__ ssum,
                                                 float* __restrict__ ssq) {
    constexpr int OC = OCTP * 16;
    constexpr int NS = DZ * KH;
    __shared__ __align__(16) half_t tA[21 * 512];  // 21504 B
    __shared__ __align__(16) half_t tB[18 * 512];  // 18432 B

    const int tid = threadIdx.x;
    const int lane = tid & 63;
    const int wv = tid >> 6;

    // ---- T1 bijective XCD remap (m204) + work decode ----
    constexpr int qc = NWG >> 3, rc = NWG & 7;
    int hw = blockIdx.x;
    int xcd = hw & 7, idx = hw >> 3;
    int work = (xcd < rc ? xcd * (qc + 1) : rc * (qc + 1) + (xcd - rc) * qc) + idx;
    int ocb, z0, x0, y0b;
    if (DZ == 3) {
        ocb = (work & 1) * 2;           // oc-half innermost: pair shares A
        int t = work >> 1;
        x0 = (t % 11) * 16; t /= 11;
        y0b = (t % 13) * 16;
        z0 = t / 13;
    } else {
        ocb = (work & 3) * 2;           // 4 oc-groups innermost
        int t = work >> 2;
        x0 = (t % 11) * 16;
        y0b = (t / 11) * 16;
        z0 = 0;
    }
    const int y0w = y0b + wv * 4;
    const bool valid = (y0w < HH);
    const int colc = lane & 15, grp = lane >> 4;

    // ---- precompute A-stage per-lane global offsets (slab-invariant, halves) ----
    // LDS phys chunk c=run*64+lane holds logical (pix,q) with
    // phys_byte = (pix<<6 | q<<4) ^ ((pix&7)<<4); inverted here.
    unsigned gofsA[6];
#pragma unroll
    for (int i = 0; i < 6; ++i) {
        int run = wv + 4 * i;
        int c = run * 64 + lane;
        if (c > 1295) c = 1295;
        int pixhi = c >> 3, s = c & 7;
        int b = ((s >> 2) ^ (pixhi >> 1)) & 1;
        int q = ((s ^ b) & 1) | ((((s >> 1) ^ pixhi) & 1) << 1);
        int pix = pixhi * 2 + b;
        int row = pix / 18, px = pix - row * 18;
        int srow = y0b + row;
        if (srow > HP - 1) srow = HP - 1;  // clamp; pad rows are zero
        gofsA[i] = (unsigned)((srow * WP + x0 + px) * 32 + q * 8);
    }

    f32x4 acc[4][2];
#pragma unroll
    for (int m = 0; m < 4; m++)
#pragma unroll
        for (int n = 0; n < 2; n++) acc[m][n] = (f32x4)(0.f);

#pragma unroll 1
    for (int s = 0; s < NS; ++s) {
        const int dz = s / KH, kh = s % KH;
        const half_t* sl = in + (size_t)kh * khstride
                           + (size_t)(z0 + dz) * (DZ == 3 ? (size_t)PPLN * 32 : 0);
        // ---- stage A via global_load_lds (linear dest, pre-swizzled source) ----
#pragma unroll
        for (int i = 0; i < 6; ++i) {
            int run = wv + 4 * i;
            if (run < 21) gload16(sl + gofsA[i], &tA[run * 512]);
        }
        // ---- stage B: 9 taps x 2 octiles, contiguous runs ----
#pragma unroll
        for (int i = 0; i < 5; ++i) {
            int r = wv + 4 * i;
            if (r < 18) {
                int tap = r >> 1, hf = r & 1;
                const half_t* g = wp + (((size_t)(dz * 9 + tap) * KH + kh) * OCTP + ocb + hf) * 512
                                  + lane * 8;
                gload16(g, &tB[r * 512]);
            }
        }
        asm volatile("s_waitcnt vmcnt(0)" ::: "memory");
        __syncthreads();

        if (valid) {
#pragma unroll
            for (int dx = 0; dx < 3; ++dx) {
                f16x8 Af[6];
#pragma unroll
                for (int r = 0; r < 6; ++r) {
                    int pix = (wv * 4 + r) * 18 + colc + dx;
                    int ah = ((pix << 5) | (grp << 3)) ^ ((pix & 7) << 3);
                    Af[r] = *(const f16x8*)&tA[ah];
                }
#pragma unroll
                for (int dy = 0; dy < 3; ++dy) {
                    f16x8 Bf[2];
#pragma unroll
                    for (int n = 0; n < 2; ++n)
                        Bf[n] = *(const f16x8*)&tB[((dy * 3 + dx) * 2 + n) * 512 + lane * 8];
#pragma unroll
                    for (int m = 0; m < 4; ++m)
#pragma unroll
                        for (int n = 0; n < 2; ++n)
                            acc[m][n] = __builtin_amdgcn_mfma_f32_16x16x32_f16(
                                Af[dy + m], Bf[n], acc[m][n], 0, 0, 0);
                }
            }
        }
        __syncthreads();
    }

    if (!valid) return;
    // epilogue: C/D layout col=lane&15 (oc), row=(lane>>4)*4+i (x)
#pragma unroll
    for (int n = 0; n < 2; ++n) {
        int oc = (ocb + n) * 16 + colc;
        float bv = bias[oc];
        float s = 0.f, q = 0.f;
#pragma unroll
        for (int m = 0; m < 4; ++m) {
            int yy = y0w + m;
#pragma unroll
            for (int i = 0; i < 4; ++i) {
                int xx = x0 + grp * 4 + i;
                float v = acc[m][n][i] + bv;
                if (STATS) { s += v; q += v * v; }
                float w = RELU ? fmaxf(v, 0.f) : v;
                out[((size_t)(z0 * HH + yy) * WW + xx) * OC + oc] = (half_t)w;
            }
        }
        if (STATS) {
            s += __shfl_xor(s, 16); s += __shfl_xor(s, 32);
            q += __shfl_xor(q, 16); q += __shfl_xor(q, 32);
            if (lane < 16) {
                atomicAdd(&ssum[oc], s);
                atomicAdd(&ssq[oc], q);
            }
        }
    }
}

// ---------------- activate: x1p = relu(bn1(y1)) into 2x 32-ch padded planes ----------------
__global__ void k_activate(const half_t* __restrict__ y1, const float* __restrict__ S,
                           const float* __restrict__ g, const float* __restrict__ be,
                           half_t* __restrict__ xp) {
    __shared__ float lA[64], lB[64];
    if (threadIdx.x < 64) {
        int c = threadIdx.x;
        float m = S[S_BN1S + c] * (1.f / 352000.f);
        float v = S[S_BN1Q + c] * (1.f / 352000.f) - m * m;
        float a = g[c] * rsqrtf(v + EPSV);
        lA[c] = a;
        lB[c] = be[c] - m * a;
    }
    __syncthreads();
    int id = blockIdx.x * 256 + threadIdx.x;
    if (id >= PVOX * 8) return;
    int c0 = (id & 7) * 8;
    int pix = id >> 3;
    int zp = pix / PPLN;
    int rem = pix - zp * PPLN;
    int yp = rem / WP;
    int xq = rem - yp * WP;
    f16x8 o;
    if (zp >= 1 && zp <= DD && yp >= 1 && yp <= HH && xq >= 1 && xq <= WW) {
        size_t p = ((size_t)((zp - 1) * HH + (yp - 1)) * WW + (xq - 1));
        f16x8 v = *(const f16x8*)(y1 + p * 64 + c0);
#pragma unroll
        for (int j = 0; j < 8; j++)
            o[j] = (half_t)fmaxf(lA[c0 + j] * (float)v[j] + lB[c0 + j], 0.f);
    } else {
#pragma unroll
        for (int j = 0; j < 8; j++) o[j] = (half_t)0.f;
    }
    int khp = c0 >> 5;
    *(f16x8*)(xp + (size_t)khp * PVOX * 32 + (size_t)pix * 32 + (c0 & 31)) = o;
}

// ---------------- BN2 + relu + depth mean (vectorized f16x8) -> 2x 32-ch padded planes ----------------
__global__ void k_depthmean(const half_t* __restrict__ y2, const float* __restrict__ S,
                            const float* __restrict__ g, const float* __restrict__ be,
                            half_t* __restrict__ plane) {
    __shared__ float lA[64], lB[64];
    if (threadIdx.x < 64) {
        int c = threadIdx.x;
        float m = S[S_BN2S + c] * (1.f / 352000.f);
        float v = S[S_BN2Q + c] * (1.f / 352000.f) - m * m;
        float a = g[c] * rsqrtf(v + EPSV);
        lA[c] = a;
        lB[c] = be[c] - m * a;
    }
    __syncthreads();
    int id = blockIdx.x * 256 + threadIdx.x;   // PPLN*8 = 287648 threads
    if (id >= PPLN * 8) return;
    int c8 = id & 7;
    int pix = id >> 3;
    int yp = pix / WP;
    int xq = pix - yp * WP;
    f16x8 o;
    if (yp >= 1 && yp <= HH && xq >= 1 && xq <= WW) {
        float A[8], B[8], sacc[8];
#pragma unroll
        for (int j = 0; j < 8; j++) {
            A[j] = lA[c8 * 8 + j];
            B[j] = lB[c8 * 8 + j];
            sacc[j] = 0.f;
        }
        const half_t* base = y2 + ((size_t)(yp - 1) * WW + (xq - 1)) * 64 + c8 * 8;
#pragma unroll
        for (int z = 0; z < DD; z++) {
            f16x8 v = *(const f16x8*)(base + (size_t)z * HWPIX * 64);
#pragma unroll
            for (int j = 0; j < 8; j++)
                sacc[j] += fmaxf(A[j] * (float)v[j] + B[j], 0.f);
        }
#pragma unroll
        for (int j = 0; j < 8; j++) o[j] = (half_t)(sacc[j] * 0.1f);
    } else {
#pragma unroll
        for (int j = 0; j < 8; j++) o[j] = (half_t)0.f;
    }
    int khp = c8 >> 2;
    *(f16x8*)(plane + (size_t)khp * PPLN * 32 + (size_t)pix * 32 + (c8 & 3) * 8) = o;
}

// ---------------- 1x1 conv 128->8 + box transforms ----------------
__global__ void k_r2(const half_t* __restrict__ r1o, const float* __restrict__ w,
                     const float* __restrict__ bias, float* __restrict__ outp) {
    __shared__ float wsm[1024];
    for (int i = threadIdx.x; i < 1024; i += 256) wsm[i] = w[i];
    __syncthreads();
    int p = blockIdx.x * 256 + threadIdx.x;
    if (p >= HWPIX) return;
    float acc[8];
#pragma unroll
    for (int o = 0; o < 8; o++) acc[o] = bias[o];
    const half_t* rb = r1o + (size_t)p * 128;
#pragma unroll 4
    for (int icb = 0; icb < 128; icb += 8) {
        f16x8 v = *(const f16x8*)(rb + icb);
#pragma unroll
        for (int j = 0; j < 8; j++) {
            float vv = (float)v[j];
#pragma unroll
            for (int o = 0; o < 8; o++) acc[o] += vv * wsm[o * 128 + icb + j];
        }
    }
    outp[0 * HWPIX + p] = acc[0];
    outp[1 * HWPIX + p] = acc[1];
    outp[2 * HWPIX + p] = acc[2];
    outp[3 * HWPIX + p] = expf(acc[3]);
    outp[4 * HWPIX + p] = expf(acc[4]);
    outp[5 * HWPIX + p] = expf(acc[5]);
    outp[6 * HWPIX + p] = tanhf(acc[6]);
    outp[7 * HWPIX + p] = 1.f / (1.f + expf(-acc[7]));
}

// ---------------- host launch ----------------
extern "C" void kernel_launch(void* const* d_in, const int* in_sizes, int n_in,
                              void* d_out, int out_size, void* d_ws, size_t ws_size,
                              hipStream_t stream) {
    const float4* voxels = (const float4*)d_in[0];
    const int* coords = (const int*)d_in[1];
    const float* w_lin = (const float*)d_in[2];
    const float* b_lin = (const float*)d_in[3];
    const float* g_bn0 = (const float*)d_in[4];
    const float* be_bn0 = (const float*)d_in[5];
    const float* w_c3a = (const float*)d_in[6];
    const float* b_c3a = (const float*)d_in[7];
    const float* g_bn1 = (const float*)d_in[8];
    const float* be_bn1 = (const float*)d_in[9];
    const float* w_c3b = (const float*)d_in[10];
    const float* b_c3b = (const float*)d_in[11];
    const float* g_bn2 = (const float*)d_in[12];
    const float* be_bn2 = (const float*)d_in[13];
    const float* w_r1 = (const float*)d_in[14];
    const float* b_r1 = (const float*)d_in[15];
    const float* w_r2 = (const float*)d_in[16];
    const float* b_r2 = (const float*)d_in[17];

    char* ws = (char*)d_ws;
    half_t* wpA = (half_t*)(ws + WPA_OFF);
    half_t* wpB = (half_t*)(ws + WPB_OFF);
    half_t* wpR1 = (half_t*)(ws + WPR1_OFF);
    float* S = (float*)(ws + STATS_OFF);
    half_t* volp = (half_t*)(ws + VOLP_OFF);
    half_t* x1p = (half_t*)(ws + X1P_OFF);
    half_t* Y = (half_t*)(ws + Y_OFF);
    half_t* plane = (half_t*)(ws + PLANE_OFF);
    half_t* r1out = (half_t*)(ws + R1OUT_OFF);
    float* outp = (float*)d_out;

    hipMemsetAsync(S, 0, 320 * sizeof(float), stream);
    hipMemsetAsync(volp, 0, (size_t)PVOX * 32 * sizeof(half_t), stream);

    // weight packs (single launch)
    k_pack_all<<<936, 256, 0, stream>>>(w_c3a, w_c3b, w_r1, wpA, wpB, wpR1);

    // VFE (BN0 coeffs folded into k_vfe_max; scatter fused)
    k_vfe_stats<<<512, 256, 0, stream>>>(voxels, w_lin, b_lin, S);
    k_vfe_max<<<1500, 256, 0, stream>>>(voxels, w_lin, b_lin, S, g_bn0, be_bn0,
                                        coords, volp);

    // conv3a (IC=32) -> y1 f16 [p][64], fused BN1 stats; NWG=2860, XCD-swizzled
    k_conv<1, 3, 4, 2860, false, true><<<2860, 256, 0, stream>>>(
        volp, 0, wpA, b_c3a, Y, S + S_BN1S, S + S_BN1Q);
    k_activate<<<13484, 256, 0, stream>>>(Y, S, g_bn1, be_bn1, x1p);

    // conv3b (IC=64 as 2x32-ch planes) -> y2 f16 [p][64], fused BN2 stats
    k_conv<2, 3, 4, 2860, false, true><<<2860, 256, 0, stream>>>(
        x1p, (size_t)PVOX * 32, wpB, b_c3b, Y, S + S_BN2S, S + S_BN2Q);

    // BN2+relu+depth-mean (vectorized) -> 2x 32-ch padded planes
    k_depthmean<<<1124, 256, 0, stream>>>(Y, S, g_bn2, be_bn2, plane);

    // RPN: r1 (2D conv, 128 oc, NWG=572, XCD-swizzled) + relu -> [p][128] f16
    k_conv<2, 1, 8, 572, true, false><<<572, 256, 0, stream>>>(
        plane, (size_t)PPLN * 32, wpR1, b_r1, r1out, nullptr, nullptr);
    k_r2<<<138, 256, 0, stream>>>(r1out, w_r2, b_r2, outp);
}